// Round 6
// baseline (396.931 us; speedup 1.0000x reference)
//
#include <hip/hip_runtime.h>
#include <cstdint>

// Problem constants (from reference)
#define N_NODES 100000
#define N_EDGES 1600000
#define D_IN    128
#define D_H     64
#define D_OUT   16
#define NB_SCAN 391   // ceil(N_NODES/256)
#define M_TILES 6250  // N_NODES / 16
#define N_PART  8     // XCD count; dst-range partitions for scatter
#define PART_SZ 12500 // N_NODES / N_PART

typedef __attribute__((ext_vector_type(8))) short short8;
typedef __attribute__((ext_vector_type(4))) float floatx4;

// float -> bf16 bits (round to nearest even)
static __device__ __forceinline__ unsigned short f2bf(float f) {
    unsigned int u = __float_as_uint(f);
    u = u + 0x7FFFu + ((u >> 16) & 1u);
    return (unsigned short)(u >> 16);
}
static __device__ __forceinline__ float bf2f(unsigned short h) {
    return __uint_as_float(((unsigned int)h) << 16);
}

// ---------------------------------------------------------------------------
// Workspace layout (bytes, 128-aligned):
//   counts   : N int32            @ 0          (400000)
//   offsets  : N+1 int32          @ 400128     (400004)
//   cursors  : N int32            @ 800256     (400000)
//   dinv     : N float            @ 1200256    (400000)
//   srcs     : E int32 (CSR)      @ 1600256    (6400000)
//   hs       : N*64 bf16 bits     @ 8000256    (12800000)
//   h2s      : N*16 float         @ 46400256   (6400000)
//   bsums    : NB_SCAN int32      @ 52800256   (1564)
// ---------------------------------------------------------------------------

__global__ void zero_kernel(int* __restrict__ p, int n) {
    int i = blockIdx.x * 256 + threadIdx.x;
    if (i < n) p[i] = 0;
}

__global__ void hist_kernel(const int* __restrict__ dst, int* __restrict__ counts) {
    int i = blockIdx.x * blockDim.x + threadIdx.x;
    int stride = gridDim.x * blockDim.x;
    for (int e = i; e < N_EDGES; e += stride) {
        int d = __builtin_nontemporal_load(&dst[e]);  // streaming: don't thrash counts
        atomicAdd(&counts[d], 1);
    }
}

// Phase A: per-block reduction of counts -> bsums[block]
__global__ __launch_bounds__(256) void blocksum_kernel(const int* __restrict__ counts,
                                                       int* __restrict__ bsums) {
    int gid = blockIdx.x * 256 + threadIdx.x;
    int c = (gid < N_NODES) ? counts[gid] : 0;
    int lane = threadIdx.x & 63;
    int wid = threadIdx.x >> 6;
    #pragma unroll
    for (int off = 32; off > 0; off >>= 1) c += __shfl_down(c, off);
    __shared__ int ws[4];
    if (lane == 0) ws[wid] = c;
    __syncthreads();
    if (threadIdx.x == 0) bsums[blockIdx.x] = ws[0] + ws[1] + ws[2] + ws[3];
}

// Phase B: single-block exclusive scan of bsums (NB_SCAN <= 512)
__global__ __launch_bounds__(512) void scan_bsums_kernel(int* __restrict__ bsums) {
    __shared__ int buf[512];
    int t = threadIdx.x;
    int v = (t < NB_SCAN) ? bsums[t] : 0;
    buf[t] = v;
    __syncthreads();
    for (int off = 1; off < 512; off <<= 1) {
        int u = (t >= off) ? buf[t - off] : 0;
        __syncthreads();
        buf[t] += u;
        __syncthreads();
    }
    if (t < NB_SCAN) bsums[t] = (t == 0) ? 0 : buf[t - 1];
}

// Phase C: block-level exclusive scan + block base -> offsets/cursors/dinv
__global__ __launch_bounds__(256) void scan_apply_kernel(const int* __restrict__ counts,
                                                         const int* __restrict__ bsums,
                                                         int* __restrict__ offsets,
                                                         int* __restrict__ cursors,
                                                         float* __restrict__ dinv) {
    int gid = blockIdx.x * 256 + threadIdx.x;
    int c = (gid < N_NODES) ? counts[gid] : 0;
    int lane = threadIdx.x & 63;
    int wid = threadIdx.x >> 6;
    int v = c;
    #pragma unroll
    for (int off = 1; off < 64; off <<= 1) {
        int u = __shfl_up(v, off);
        if (lane >= off) v += u;
    }
    __shared__ int wsum[4];
    if (lane == 63) wsum[wid] = v;
    __syncthreads();
    int wadd = 0;
    for (int i = 0; i < wid; ++i) wadd += wsum[i];
    int incl = v + wadd;
    int base = bsums[blockIdx.x];
    if (gid < N_NODES) {
        int excl = base + incl - c;
        offsets[gid] = excl;
        cursors[gid] = excl;
        dinv[gid] = rsqrtf((float)c + 1.0f);  // +1 self loop; deg >= 1 always
        if (gid == N_NODES - 1) offsets[N_NODES] = base + incl;
    }
}

// XCD-partitioned CSR scatter (partition = blockIdx & 7). Streaming dst/src
// reads are NON-TEMPORAL so they don't evict the partially-filled dirty
// srcs lines from this XCD's L2 (the residual 11x write amplification in R5).
__global__ __launch_bounds__(256) void scatter_kernel(const int* __restrict__ src,
                                                      const int* __restrict__ dst,
                                                      int* __restrict__ cursors,
                                                      int* __restrict__ srcs) {
    int part = blockIdx.x & (N_PART - 1);
    int lo = part * PART_SZ;
    int hi = lo + PART_SZ;
    int bi = blockIdx.x >> 3;            // block index within partition
    int nb = gridDim.x >> 3;             // blocks per partition
    int tid = bi * 256 + threadIdx.x;
    int stride = nb * 256;
    for (int e = tid; e < N_EDGES; e += stride) {
        int d = __builtin_nontemporal_load(&dst[e]);
        if (d >= lo && d < hi) {
            int s = __builtin_nontemporal_load(&src[e]);
            int p = atomicAdd(&cursors[d], 1);
            srcs[p] = s;
        }
    }
}

// ---------------------------------------------------------------------------
// gemm1 via MFMA bf16x2 split precision.
// ---------------------------------------------------------------------------
__global__ __launch_bounds__(256) void gemm1_mfma_kernel(const float* __restrict__ x,
                                                         const float* __restrict__ W1,
                                                         const float* __restrict__ dinv,
                                                         unsigned short* __restrict__ hs) {
    __shared__ unsigned short bhi_lds[8192];  // [ (kc*4+nt)*64 + lane ][8]
    __shared__ unsigned short blo_lds[8192];

    for (int e = threadIdx.x; e < 8192; e += 256) {
        int j    = e & 7;
        int lane = (e >> 3) & 63;
        int pair = e >> 9;          // 0..15 = kc*4 + nt
        int kc   = pair >> 2;
        int nt   = pair & 3;
        int k = kc * 32 + (lane >> 4) * 8 + j;
        int n = nt * 16 + (lane & 15);
        float w = W1[k * D_H + n];
        unsigned short hi = f2bf(w);
        float lo = w - bf2f(hi);
        bhi_lds[e] = hi;
        blo_lds[e] = f2bf(lo);
    }
    __syncthreads();

    int wid  = threadIdx.x >> 6;
    int lane = threadIdx.x & 63;
    int quad = lane >> 4;
    int m    = lane & 15;

    int tile = blockIdx.x * 4 + wid;
    if (tile >= M_TILES) return;
    int mbase = tile * 16;

    const float* xr = x + (size_t)(mbase + m) * D_IN + quad * 8;
    short8 ahi[4], alo[4];
    #pragma unroll
    for (int kc = 0; kc < 4; ++kc) {
        floatx4 v0 = *(const floatx4*)(xr + kc * 32);
        floatx4 v1 = *(const floatx4*)(xr + kc * 32 + 4);
        float f[8] = {v0.x, v0.y, v0.z, v0.w, v1.x, v1.y, v1.z, v1.w};
        #pragma unroll
        for (int j = 0; j < 8; ++j) {
            unsigned short hi = f2bf(f[j]);
            float lo = f[j] - bf2f(hi);
            ahi[kc][j] = (short)hi;
            alo[kc][j] = (short)f2bf(lo);
        }
    }

    floatx4 acc[4] = {{0.f,0.f,0.f,0.f},{0.f,0.f,0.f,0.f},{0.f,0.f,0.f,0.f},{0.f,0.f,0.f,0.f}};
    #pragma unroll
    for (int kc = 0; kc < 4; ++kc) {
        #pragma unroll
        for (int nt = 0; nt < 4; ++nt) {
            int fo = ((kc * 4 + nt) * 64 + lane) * 8;
            short8 bhi = *(const short8*)&bhi_lds[fo];
            short8 blo = *(const short8*)&blo_lds[fo];
            acc[nt] = __builtin_amdgcn_mfma_f32_16x16x32_bf16(ahi[kc], bhi, acc[nt], 0, 0, 0);
            acc[nt] = __builtin_amdgcn_mfma_f32_16x16x32_bf16(ahi[kc], blo, acc[nt], 0, 0, 0);
            acc[nt] = __builtin_amdgcn_mfma_f32_16x16x32_bf16(alo[kc], bhi, acc[nt], 0, 0, 0);
        }
    }

    float dv[4];
    #pragma unroll
    for (int r = 0; r < 4; ++r) dv[r] = dinv[mbase + quad * 4 + r];
    #pragma unroll
    for (int nt = 0; nt < 4; ++nt) {
        int col = nt * 16 + m;
        #pragma unroll
        for (int r = 0; r < 4; ++r) {
            int row = mbase + quad * 4 + r;
            hs[row * D_H + col] = f2bf(acc[nt][r] * dv[r]);
        }
    }
}

// Fused layer-1 aggregation + ReLU + layer-2 linear:
//   relu_i[c] = relu(dinv[i]*(hs[i][c] + sum_{j->i} hs[j][c]) + b1[c])   (c = lane)
//   h2s[i][o] = dinv[i] * sum_c relu_i[c] * W2[c][o]                     (o = 0..15)
// One wave per node; projection via per-lane W2 row + xor-butterfly reduce.
// Eliminates the 51 MB relu_buf round trip and the separate gemm2 dispatch.
__global__ __launch_bounds__(256) void agg1_fused_kernel(const unsigned short* __restrict__ hs,
                                                         const int* __restrict__ offsets,
                                                         const int* __restrict__ srcs,
                                                         const float* __restrict__ dinv,
                                                         const float* __restrict__ b1,
                                                         const float* __restrict__ W2,
                                                         float* __restrict__ h2s) {
    int wave = (blockIdx.x * blockDim.x + threadIdx.x) >> 6;
    int lane = threadIdx.x & 63;
    int nwaves = (gridDim.x * blockDim.x) >> 6;

    // per-lane W2 row: W2[lane][0..15]  (row-major [64][16])
    float w2r[16];
    #pragma unroll
    for (int c = 0; c < 16; ++c) w2r[c] = W2[lane * D_OUT + c];
    float bias = b1[lane];

    for (int node = wave; node < N_NODES; node += nwaves) {
        int beg = offsets[node], end = offsets[node + 1];
        float acc = bf2f(hs[node * D_H + lane]);  // self loop
        int e = beg;
        for (; e + 8 <= end; e += 8) {
            int j0 = srcs[e + 0], j1 = srcs[e + 1], j2 = srcs[e + 2], j3 = srcs[e + 3];
            int j4 = srcs[e + 4], j5 = srcs[e + 5], j6 = srcs[e + 6], j7 = srcs[e + 7];
            float v0 = bf2f(hs[j0 * D_H + lane]);
            float v1 = bf2f(hs[j1 * D_H + lane]);
            float v2 = bf2f(hs[j2 * D_H + lane]);
            float v3 = bf2f(hs[j3 * D_H + lane]);
            float v4 = bf2f(hs[j4 * D_H + lane]);
            float v5 = bf2f(hs[j5 * D_H + lane]);
            float v6 = bf2f(hs[j6 * D_H + lane]);
            float v7 = bf2f(hs[j7 * D_H + lane]);
            acc += ((v0 + v1) + (v2 + v3)) + ((v4 + v5) + (v6 + v7));
        }
        for (; e < end; ++e) {
            acc += bf2f(hs[srcs[e] * D_H + lane]);
        }
        float dv = dinv[node];
        float r = fmaxf(acc * dv + bias, 0.f);

        // project 64 -> 16: p[c] = sum over lanes of r * W2[lane][c]
        float p[16];
        #pragma unroll
        for (int c = 0; c < 16; ++c) p[c] = r * w2r[c];
        #pragma unroll
        for (int off = 1; off < 64; off <<= 1) {
            #pragma unroll
            for (int c = 0; c < 16; ++c) p[c] += __shfl_xor(p[c], off);
        }
        // lanes 0..15 write column = lane
        float sel = 0.f;
        #pragma unroll
        for (int c = 0; c < 16; ++c) sel = (lane == c) ? p[c] : sel;
        if (lane < 16) h2s[node * D_OUT + lane] = sel * dv;
    }
}

// out[i][c] = dinv[i]*(h2s[i][c] + sum_{j->i} h2s[j][c]) + b2[c]
// 16 threads per node; edge loop unrolled x8.
__global__ __launch_bounds__(256) void agg2_kernel(const float* __restrict__ h2s,
                                                   const int* __restrict__ offsets,
                                                   const int* __restrict__ srcs,
                                                   const float* __restrict__ dinv,
                                                   const float* __restrict__ b2,
                                                   float* __restrict__ out) {
    int col = threadIdx.x & 15;
    int nidx = (blockIdx.x * blockDim.x + threadIdx.x) >> 4;
    int stride = (gridDim.x * blockDim.x) >> 4;
    for (int node = nidx; node < N_NODES; node += stride) {
        int beg = offsets[node], end = offsets[node + 1];
        float acc = h2s[node * D_OUT + col];  // self loop
        int e = beg;
        for (; e + 8 <= end; e += 8) {
            int j0 = srcs[e + 0], j1 = srcs[e + 1], j2 = srcs[e + 2], j3 = srcs[e + 3];
            int j4 = srcs[e + 4], j5 = srcs[e + 5], j6 = srcs[e + 6], j7 = srcs[e + 7];
            float v0 = h2s[j0 * D_OUT + col];
            float v1 = h2s[j1 * D_OUT + col];
            float v2 = h2s[j2 * D_OUT + col];
            float v3 = h2s[j3 * D_OUT + col];
            float v4 = h2s[j4 * D_OUT + col];
            float v5 = h2s[j5 * D_OUT + col];
            float v6 = h2s[j6 * D_OUT + col];
            float v7 = h2s[j7 * D_OUT + col];
            acc += ((v0 + v1) + (v2 + v3)) + ((v4 + v5) + (v6 + v7));
        }
        for (; e < end; ++e) {
            acc += h2s[srcs[e] * D_OUT + col];
        }
        out[node * D_OUT + col] = acc * dinv[node] + b2[col];
    }
}

extern "C" void kernel_launch(void* const* d_in, const int* in_sizes, int n_in,
                              void* d_out, int out_size, void* d_ws, size_t ws_size,
                              hipStream_t stream) {
    const float* x  = (const float*)d_in[0];
    const int*   ei = (const int*)d_in[1];
    const float* W1 = (const float*)d_in[2];
    const float* b1 = (const float*)d_in[3];
    const float* W2 = (const float*)d_in[4];
    const float* b2 = (const float*)d_in[5];
    float* out = (float*)d_out;

    const int* src = ei;             // edge_index[0]
    const int* dst = ei + N_EDGES;   // edge_index[1]

    char* w = (char*)d_ws;
    int*   counts   = (int*)(w + 0);
    int*   offsets  = (int*)(w + 400128);
    int*   cursors  = (int*)(w + 800256);
    float* dinv     = (float*)(w + 1200256);
    int*   srcs     = (int*)(w + 1600256);
    unsigned short* hs = (unsigned short*)(w + 8000256);
    float* h2s      = (float*)(w + 46400256);
    int*   bsums    = (int*)(w + 52800256);

    zero_kernel<<<(N_NODES + 255) / 256, 256, 0, stream>>>(counts, N_NODES);
    hist_kernel<<<2048, 256, 0, stream>>>(dst, counts);
    blocksum_kernel<<<NB_SCAN, 256, 0, stream>>>(counts, bsums);
    scan_bsums_kernel<<<1, 512, 0, stream>>>(bsums);
    scan_apply_kernel<<<NB_SCAN, 256, 0, stream>>>(counts, bsums, offsets, cursors, dinv);
    scatter_kernel<<<2048, 256, 0, stream>>>(src, dst, cursors, srcs);
    gemm1_mfma_kernel<<<(M_TILES + 3) / 4, 256, 0, stream>>>(x, W1, dinv, hs);
    agg1_fused_kernel<<<6250, 256, 0, stream>>>(hs, offsets, srcs, dinv, b1, W2, h2s);
    agg2_kernel<<<6250, 256, 0, stream>>>(h2s, offsets, srcs, dinv, b2, out);
}

// Round 7
// 355.829 us; speedup vs baseline: 1.1155x; 1.1155x over previous
//
#include <hip/hip_runtime.h>
#include <cstdint>

// Problem constants (from reference)
#define N_NODES 100000
#define N_EDGES 1600000
#define D_IN    128
#define D_H     64
#define D_OUT   16
#define NB_SCAN 391   // ceil(N_NODES/256)
#define M_TILES 6250  // N_NODES / 16
#define N_PART  8     // XCD count; dst-range partitions for scatter
#define PART_SZ 12500 // N_NODES / N_PART

typedef __attribute__((ext_vector_type(8))) short short8;
typedef __attribute__((ext_vector_type(4))) float floatx4;

// float -> bf16 bits (round to nearest even)
static __device__ __forceinline__ unsigned short f2bf(float f) {
    unsigned int u = __float_as_uint(f);
    u = u + 0x7FFFu + ((u >> 16) & 1u);
    return (unsigned short)(u >> 16);
}
static __device__ __forceinline__ float bf2f(unsigned short h) {
    return __uint_as_float(((unsigned int)h) << 16);
}

// ---------------------------------------------------------------------------
// Workspace layout (bytes, 128-aligned):
//   counts   : N int32            @ 0          (400000)
//   offsets  : N+1 int32          @ 400128     (400004)
//   cursors  : N int32            @ 800256     (400000)
//   dinv     : N float            @ 1200256    (400000)
//   srcs     : E int32 (CSR)      @ 1600256    (6400000)
//   hs       : N*64 bf16 bits     @ 8000256    (12800000)
//   h2s      : N*16 float         @ 46400256   (6400000)
//   bsums    : NB_SCAN int32      @ 52800256   (1564)
// ---------------------------------------------------------------------------

__global__ void zero_kernel(int* __restrict__ p, int n) {
    int i = blockIdx.x * 256 + threadIdx.x;
    if (i < n) p[i] = 0;
}

__global__ void hist_kernel(const int* __restrict__ dst, int* __restrict__ counts) {
    int i = blockIdx.x * blockDim.x + threadIdx.x;
    int stride = gridDim.x * blockDim.x;
    for (int e = i; e < N_EDGES; e += stride) {
        int d = __builtin_nontemporal_load(&dst[e]);  // streaming: don't thrash counts
        atomicAdd(&counts[d], 1);
    }
}

// Phase A: per-block reduction of counts -> bsums[block]
__global__ __launch_bounds__(256) void blocksum_kernel(const int* __restrict__ counts,
                                                       int* __restrict__ bsums) {
    int gid = blockIdx.x * 256 + threadIdx.x;
    int c = (gid < N_NODES) ? counts[gid] : 0;
    int lane = threadIdx.x & 63;
    int wid = threadIdx.x >> 6;
    #pragma unroll
    for (int off = 32; off > 0; off >>= 1) c += __shfl_down(c, off);
    __shared__ int ws[4];
    if (lane == 0) ws[wid] = c;
    __syncthreads();
    if (threadIdx.x == 0) bsums[blockIdx.x] = ws[0] + ws[1] + ws[2] + ws[3];
}

// Phase B: single-block exclusive scan of bsums (NB_SCAN <= 512)
__global__ __launch_bounds__(512) void scan_bsums_kernel(int* __restrict__ bsums) {
    __shared__ int buf[512];
    int t = threadIdx.x;
    int v = (t < NB_SCAN) ? bsums[t] : 0;
    buf[t] = v;
    __syncthreads();
    for (int off = 1; off < 512; off <<= 1) {
        int u = (t >= off) ? buf[t - off] : 0;
        __syncthreads();
        buf[t] += u;
        __syncthreads();
    }
    if (t < NB_SCAN) bsums[t] = (t == 0) ? 0 : buf[t - 1];
}

// Phase C: block-level exclusive scan + block base -> offsets/cursors/dinv
__global__ __launch_bounds__(256) void scan_apply_kernel(const int* __restrict__ counts,
                                                         const int* __restrict__ bsums,
                                                         int* __restrict__ offsets,
                                                         int* __restrict__ cursors,
                                                         float* __restrict__ dinv) {
    int gid = blockIdx.x * 256 + threadIdx.x;
    int c = (gid < N_NODES) ? counts[gid] : 0;
    int lane = threadIdx.x & 63;
    int wid = threadIdx.x >> 6;
    int v = c;
    #pragma unroll
    for (int off = 1; off < 64; off <<= 1) {
        int u = __shfl_up(v, off);
        if (lane >= off) v += u;
    }
    __shared__ int wsum[4];
    if (lane == 63) wsum[wid] = v;
    __syncthreads();
    int wadd = 0;
    for (int i = 0; i < wid; ++i) wadd += wsum[i];
    int incl = v + wadd;
    int base = bsums[blockIdx.x];
    if (gid < N_NODES) {
        int excl = base + incl - c;
        offsets[gid] = excl;
        cursors[gid] = excl;
        dinv[gid] = rsqrtf((float)c + 1.0f);  // +1 self loop; deg >= 1 always
        if (gid == N_NODES - 1) offsets[N_NODES] = base + incl;
    }
}

// XCD-partitioned CSR scatter (partition = blockIdx & 7) with non-temporal
// streaming reads (keeps dirty srcs lines resident in this XCD's L2).
__global__ __launch_bounds__(256) void scatter_kernel(const int* __restrict__ src,
                                                      const int* __restrict__ dst,
                                                      int* __restrict__ cursors,
                                                      int* __restrict__ srcs) {
    int part = blockIdx.x & (N_PART - 1);
    int lo = part * PART_SZ;
    int hi = lo + PART_SZ;
    int bi = blockIdx.x >> 3;            // block index within partition
    int nb = gridDim.x >> 3;             // blocks per partition
    int tid = bi * 256 + threadIdx.x;
    int stride = nb * 256;
    for (int e = tid; e < N_EDGES; e += stride) {
        int d = __builtin_nontemporal_load(&dst[e]);
        if (d >= lo && d < hi) {
            int s = __builtin_nontemporal_load(&src[e]);
            int p = atomicAdd(&cursors[d], 1);
            srcs[p] = s;
        }
    }
}

// ---------------------------------------------------------------------------
// gemm1 via MFMA bf16x2 split precision.
// ---------------------------------------------------------------------------
__global__ __launch_bounds__(256) void gemm1_mfma_kernel(const float* __restrict__ x,
                                                         const float* __restrict__ W1,
                                                         const float* __restrict__ dinv,
                                                         unsigned short* __restrict__ hs) {
    __shared__ unsigned short bhi_lds[8192];  // [ (kc*4+nt)*64 + lane ][8]
    __shared__ unsigned short blo_lds[8192];

    for (int e = threadIdx.x; e < 8192; e += 256) {
        int j    = e & 7;
        int lane = (e >> 3) & 63;
        int pair = e >> 9;          // 0..15 = kc*4 + nt
        int kc   = pair >> 2;
        int nt   = pair & 3;
        int k = kc * 32 + (lane >> 4) * 8 + j;
        int n = nt * 16 + (lane & 15);
        float w = W1[k * D_H + n];
        unsigned short hi = f2bf(w);
        float lo = w - bf2f(hi);
        bhi_lds[e] = hi;
        blo_lds[e] = f2bf(lo);
    }
    __syncthreads();

    int wid  = threadIdx.x >> 6;
    int lane = threadIdx.x & 63;
    int quad = lane >> 4;
    int m    = lane & 15;

    int tile = blockIdx.x * 4 + wid;
    if (tile >= M_TILES) return;
    int mbase = tile * 16;

    const float* xr = x + (size_t)(mbase + m) * D_IN + quad * 8;
    short8 ahi[4], alo[4];
    #pragma unroll
    for (int kc = 0; kc < 4; ++kc) {
        floatx4 v0 = *(const floatx4*)(xr + kc * 32);
        floatx4 v1 = *(const floatx4*)(xr + kc * 32 + 4);
        float f[8] = {v0.x, v0.y, v0.z, v0.w, v1.x, v1.y, v1.z, v1.w};
        #pragma unroll
        for (int j = 0; j < 8; ++j) {
            unsigned short hi = f2bf(f[j]);
            float lo = f[j] - bf2f(hi);
            ahi[kc][j] = (short)hi;
            alo[kc][j] = (short)f2bf(lo);
        }
    }

    floatx4 acc[4] = {{0.f,0.f,0.f,0.f},{0.f,0.f,0.f,0.f},{0.f,0.f,0.f,0.f},{0.f,0.f,0.f,0.f}};
    #pragma unroll
    for (int kc = 0; kc < 4; ++kc) {
        #pragma unroll
        for (int nt = 0; nt < 4; ++nt) {
            int fo = ((kc * 4 + nt) * 64 + lane) * 8;
            short8 bhi = *(const short8*)&bhi_lds[fo];
            short8 blo = *(const short8*)&blo_lds[fo];
            acc[nt] = __builtin_amdgcn_mfma_f32_16x16x32_bf16(ahi[kc], bhi, acc[nt], 0, 0, 0);
            acc[nt] = __builtin_amdgcn_mfma_f32_16x16x32_bf16(ahi[kc], blo, acc[nt], 0, 0, 0);
            acc[nt] = __builtin_amdgcn_mfma_f32_16x16x32_bf16(alo[kc], bhi, acc[nt], 0, 0, 0);
        }
    }

    float dv[4];
    #pragma unroll
    for (int r = 0; r < 4; ++r) dv[r] = dinv[mbase + quad * 4 + r];
    #pragma unroll
    for (int nt = 0; nt < 4; ++nt) {
        int col = nt * 16 + m;
        #pragma unroll
        for (int r = 0; r < 4; ++r) {
            int row = mbase + quad * 4 + r;
            hs[row * D_H + col] = f2bf(acc[nt][r] * dv[r]);
        }
    }
}

// Fused layer-1 aggregation + ReLU + layer-2 linear.
//   r[c]    = relu(dinv[i]*(hs[i][c] + sum_{j->i} hs[j][c]) + b1[c])   (c = lane)
//   h2s[i][o] = dinv[i] * sum_c r[c] * W2[c][o]
// Projection via wave-private LDS transpose (DS pipe is in-order per wave, no
// barrier): stage r, lane q*16+c dots a 16-row slice of W2[:,c] (same-address
// broadcast reads), then 2 shfl_xor to reduce over q. ~19 DS ops/node vs the
// R6 butterfly's 96 shuffles/node (which cost +52 us).
__global__ __launch_bounds__(256) void agg1_fused_kernel(const unsigned short* __restrict__ hs,
                                                         const int* __restrict__ offsets,
                                                         const int* __restrict__ srcs,
                                                         const float* __restrict__ dinv,
                                                         const float* __restrict__ b1,
                                                         const float* __restrict__ W2,
                                                         float* __restrict__ h2s) {
    __shared__ float rbuf[256];  // wave w owns rbuf[w*64 .. w*64+63]
    int wid  = threadIdx.x >> 6;
    int lane = threadIdx.x & 63;
    int wave = (blockIdx.x * blockDim.x + threadIdx.x) >> 6;
    int nwaves = (gridDim.x * blockDim.x) >> 6;

    int q = lane >> 4;   // 0..3 : which 16-row slice of W2 this lane covers
    int c = lane & 15;   // output column
    float w2c[16];       // W2[q*16+j][c], j=0..15
    #pragma unroll
    for (int j = 0; j < 16; ++j) w2c[j] = W2[(q * 16 + j) * D_OUT + c];
    float bias = b1[lane];
    float* myr = &rbuf[wid * 64];

    for (int node = wave; node < N_NODES; node += nwaves) {
        int beg = offsets[node], end = offsets[node + 1];
        float acc = bf2f(hs[node * D_H + lane]);  // self loop
        int e = beg;
        for (; e + 8 <= end; e += 8) {
            int j0 = srcs[e + 0], j1 = srcs[e + 1], j2 = srcs[e + 2], j3 = srcs[e + 3];
            int j4 = srcs[e + 4], j5 = srcs[e + 5], j6 = srcs[e + 6], j7 = srcs[e + 7];
            float v0 = bf2f(hs[j0 * D_H + lane]);
            float v1 = bf2f(hs[j1 * D_H + lane]);
            float v2 = bf2f(hs[j2 * D_H + lane]);
            float v3 = bf2f(hs[j3 * D_H + lane]);
            float v4 = bf2f(hs[j4 * D_H + lane]);
            float v5 = bf2f(hs[j5 * D_H + lane]);
            float v6 = bf2f(hs[j6 * D_H + lane]);
            float v7 = bf2f(hs[j7 * D_H + lane]);
            acc += ((v0 + v1) + (v2 + v3)) + ((v4 + v5) + (v6 + v7));
        }
        for (; e < end; ++e) {
            acc += bf2f(hs[srcs[e] * D_H + lane]);
        }
        float dv = dinv[node];
        float r = fmaxf(acc * dv + bias, 0.f);

        // wave-synchronous LDS transpose projection
        myr[lane] = r;
        float part = 0.f;
        #pragma unroll
        for (int j = 0; j < 16; ++j) part += myr[q * 16 + j] * w2c[j];
        part += __shfl_xor(part, 16);
        part += __shfl_xor(part, 32);
        if (lane < 16) h2s[node * D_OUT + lane] = part * dv;
    }
}

// out[i][c] = dinv[i]*(h2s[i][c] + sum_{j->i} h2s[j][c]) + b2[c]
// 16 threads per node; edge loop unrolled x8.
__global__ __launch_bounds__(256) void agg2_kernel(const float* __restrict__ h2s,
                                                   const int* __restrict__ offsets,
                                                   const int* __restrict__ srcs,
                                                   const float* __restrict__ dinv,
                                                   const float* __restrict__ b2,
                                                   float* __restrict__ out) {
    int col = threadIdx.x & 15;
    int nidx = (blockIdx.x * blockDim.x + threadIdx.x) >> 4;
    int stride = (gridDim.x * blockDim.x) >> 4;
    for (int node = nidx; node < N_NODES; node += stride) {
        int beg = offsets[node], end = offsets[node + 1];
        float acc = h2s[node * D_OUT + col];  // self loop
        int e = beg;
        for (; e + 8 <= end; e += 8) {
            int j0 = srcs[e + 0], j1 = srcs[e + 1], j2 = srcs[e + 2], j3 = srcs[e + 3];
            int j4 = srcs[e + 4], j5 = srcs[e + 5], j6 = srcs[e + 6], j7 = srcs[e + 7];
            float v0 = h2s[j0 * D_OUT + col];
            float v1 = h2s[j1 * D_OUT + col];
            float v2 = h2s[j2 * D_OUT + col];
            float v3 = h2s[j3 * D_OUT + col];
            float v4 = h2s[j4 * D_OUT + col];
            float v5 = h2s[j5 * D_OUT + col];
            float v6 = h2s[j6 * D_OUT + col];
            float v7 = h2s[j7 * D_OUT + col];
            acc += ((v0 + v1) + (v2 + v3)) + ((v4 + v5) + (v6 + v7));
        }
        for (; e < end; ++e) {
            acc += h2s[srcs[e] * D_OUT + col];
        }
        out[node * D_OUT + col] = acc * dinv[node] + b2[col];
    }
}

extern "C" void kernel_launch(void* const* d_in, const int* in_sizes, int n_in,
                              void* d_out, int out_size, void* d_ws, size_t ws_size,
                              hipStream_t stream) {
    const float* x  = (const float*)d_in[0];
    const int*   ei = (const int*)d_in[1];
    const float* W1 = (const float*)d_in[2];
    const float* b1 = (const float*)d_in[3];
    const float* W2 = (const float*)d_in[4];
    const float* b2 = (const float*)d_in[5];
    float* out = (float*)d_out;

    const int* src = ei;             // edge_index[0]
    const int* dst = ei + N_EDGES;   // edge_index[1]

    char* w = (char*)d_ws;
    int*   counts   = (int*)(w + 0);
    int*   offsets  = (int*)(w + 400128);
    int*   cursors  = (int*)(w + 800256);
    float* dinv     = (float*)(w + 1200256);
    int*   srcs     = (int*)(w + 1600256);
    unsigned short* hs = (unsigned short*)(w + 8000256);
    float* h2s      = (float*)(w + 46400256);
    int*   bsums    = (int*)(w + 52800256);

    zero_kernel<<<(N_NODES + 255) / 256, 256, 0, stream>>>(counts, N_NODES);
    hist_kernel<<<2048, 256, 0, stream>>>(dst, counts);
    blocksum_kernel<<<NB_SCAN, 256, 0, stream>>>(counts, bsums);
    scan_bsums_kernel<<<1, 512, 0, stream>>>(bsums);
    scan_apply_kernel<<<NB_SCAN, 256, 0, stream>>>(counts, bsums, offsets, cursors, dinv);
    scatter_kernel<<<2048, 256, 0, stream>>>(src, dst, cursors, srcs);
    gemm1_mfma_kernel<<<(M_TILES + 3) / 4, 256, 0, stream>>>(x, W1, dinv, hs);
    agg1_fused_kernel<<<6250, 256, 0, stream>>>(hs, offsets, srcs, dinv, b1, W2, h2s);
    agg2_kernel<<<6250, 256, 0, stream>>>(h2s, offsets, srcs, dinv, b2, out);
}

// Round 8
// 244.311 us; speedup vs baseline: 1.6247x; 1.4565x over previous
//
#include <hip/hip_runtime.h>
#include <cstdint>

// Problem constants (from reference)
#define N_NODES 100000
#define N_EDGES 1600000
#define D_IN    128
#define D_H     64
#define D_OUT   16
#define M_TILES 6250  // N_NODES / 16

// Bucket sort parameters
#define NBKT   512
#define NPB    196           // nodes per bucket; 512*196 = 100352 >= N
#define BCAP   4096          // per-bucket region capacity (mean 3125, sd 56 -> +17 sigma)
#define TILE_E 4096          // edges per bin tile (256 thr x 16); N_EDGES % 16 == 0
#define NTILES ((N_EDGES + TILE_E - 1) / TILE_E)   // 391
#define G1     128           // bin_kernel blocks

typedef __attribute__((ext_vector_type(8))) short short8;
typedef __attribute__((ext_vector_type(4))) float floatx4;

// float -> bf16 bits (round to nearest even)
static __device__ __forceinline__ unsigned short f2bf(float f) {
    unsigned int u = __float_as_uint(f);
    u = u + 0x7FFFu + ((u >> 16) & 1u);
    return (unsigned short)(u >> 16);
}
static __device__ __forceinline__ float bf2f(unsigned short h) {
    return __uint_as_float(((unsigned int)h) << 16);
}

// ---------------------------------------------------------------------------
// Workspace layout (bytes, 128-aligned):
//   cursors : NBKT int          @ 0         (2048)
//   bases   : NBKT int          @ 2048      (2048)
//   offsets : N+1 int           @ 4096      (400004)
//   dinv    : N float           @ 404224    (400000)
//   srcs    : E int (CSR)       @ 804224    (6400000)
//   hs      : N*64 bf16 bits    @ 7204224   (12800000)
//   h2s     : N*16 float        @ 20004224  (6400000)
//   region  : NBKT*BCAP int     @ 26404224  (8388608)
// total ~34.8 MB
// ---------------------------------------------------------------------------

__global__ __launch_bounds__(512) void zero_small_kernel(int* __restrict__ cursors) {
    cursors[threadIdx.x] = 0;
}

// Pass 1: tile-synchronous binning. Per 4096-edge tile: LDS hist over 512
// buckets -> one global atomicAdd per non-empty bucket -> append packed
// (dst_local << 17 | src) entries to the bucket's region (burst appends).
__global__ __launch_bounds__(256) void bin_kernel(const int* __restrict__ src,
                                                  const int* __restrict__ dst,
                                                  int* __restrict__ cursors,
                                                  int* __restrict__ region) {
    __shared__ int hcnt[NBKT];
    __shared__ int hbase[NBKT];
    const int t = threadIdx.x;
    for (int tile = blockIdx.x; tile < NTILES; tile += gridDim.x) {
        for (int i = t; i < NBKT; i += 256) hcnt[i] = 0;
        __syncthreads();
        int e0 = tile * TILE_E + t * 16;
        int pk[16], bk[16], rk[16];
        bool full = (e0 + 16 <= N_EDGES);   // all-or-nothing: N_EDGES % 16 == 0
        if (full) {
            const int4* dp = (const int4*)(dst + e0);
            const int4* sp = (const int4*)(src + e0);
            int dv[16], sv[16];
            #pragma unroll
            for (int q = 0; q < 4; ++q) {
                int4 d4 = dp[q]; int4 s4 = sp[q];
                dv[4*q+0]=d4.x; dv[4*q+1]=d4.y; dv[4*q+2]=d4.z; dv[4*q+3]=d4.w;
                sv[4*q+0]=s4.x; sv[4*q+1]=s4.y; sv[4*q+2]=s4.z; sv[4*q+3]=s4.w;
            }
            #pragma unroll
            for (int k = 0; k < 16; ++k) {
                int d = dv[k];
                int b = d / NPB;          // const divide -> mul/shift
                bk[k] = b;
                pk[k] = ((d - b * NPB) << 17) | sv[k];
                rk[k] = atomicAdd(&hcnt[b], 1);
            }
        }
        __syncthreads();
        for (int i = t; i < NBKT; i += 256) {
            int c = hcnt[i];
            if (c > 0) hbase[i] = atomicAdd(&cursors[i], c);
        }
        __syncthreads();
        if (full) {
            #pragma unroll
            for (int k = 0; k < 16; ++k)
                region[bk[k] * BCAP + hbase[bk[k]] + rk[k]] = pk[k];
        }
        __syncthreads();   // protect hcnt before next tile's clear
    }
}

// Exclusive scan of the 512 bucket counts -> bases. One block.
__global__ __launch_bounds__(512) void bucket_scan_kernel(const int* __restrict__ cursors,
                                                          int* __restrict__ bases) {
    __shared__ int buf[512];
    int t = threadIdx.x;
    int v = cursors[t];
    buf[t] = v;
    __syncthreads();
    for (int off = 1; off < 512; off <<= 1) {
        int u = (t >= off) ? buf[t - off] : 0;
        __syncthreads();
        buf[t] += u;
        __syncthreads();
    }
    bases[t] = buf[t] - v;   // exclusive
}

// Pass 2: one block per bucket. Local hist+scan over 196 nodes -> offsets/dinv,
// sort entries into LDS, write CSR segment SEQUENTIALLY (full-line stores).
__global__ __launch_bounds__(256) void build_kernel(const int* __restrict__ cursors,
                                                    const int* __restrict__ bases,
                                                    const int* __restrict__ region,
                                                    int* __restrict__ offsets,
                                                    float* __restrict__ dinv,
                                                    int* __restrict__ srcs) {
    __shared__ int lhist[NPB];        // counts, then running cursors
    __shared__ int lscan[NPB + 1];
    __shared__ int sbuf[256];
    __shared__ int srt[BCAP];
    int b = blockIdx.x;
    int cnt = cursors[b];
    int base = bases[b];
    const int* reg = region + b * BCAP;
    int t = threadIdx.x;

    for (int i = t; i < NPB; i += 256) lhist[i] = 0;
    __syncthreads();
    for (int i = t; i < cnt; i += 256) {
        int ln = reg[i] >> 17;
        atomicAdd(&lhist[ln], 1);
    }
    __syncthreads();
    // exclusive scan of lhist[0..NPB-1]
    int v = (t < NPB) ? lhist[t] : 0;
    sbuf[t] = v;
    __syncthreads();
    for (int off = 1; off < 256; off <<= 1) {
        int u = (t >= off) ? sbuf[t - off] : 0;
        __syncthreads();
        sbuf[t] += u;
        __syncthreads();
    }
    int incl = sbuf[t];
    if (t < NPB) lscan[t] = incl - v;
    if (t == NPB - 1) lscan[NPB] = incl;
    __syncthreads();
    if (t < NPB) lhist[t] = incl - v;   // running cursor = exclusive scan
    __syncthreads();

    // offsets + dinv for this bucket's node range
    int node0 = b * NPB;
    int nlim = N_NODES - node0;
    if (nlim > NPB) nlim = NPB;
    if (t < nlim) {
        offsets[node0 + t] = base + lscan[t];
        int c = lscan[t + 1] - lscan[t];
        dinv[node0 + t] = rsqrtf((float)c + 1.0f);   // +1 self loop
    }
    if (b == (N_NODES - 1) / NPB && t == 0) offsets[N_NODES] = base + cnt;

    // place entries into sorted LDS buffer
    for (int i = t; i < cnt; i += 256) {
        int p = reg[i];
        int ln = p >> 17;
        int pos = atomicAdd(&lhist[ln], 1);
        srt[pos] = p & 0x1FFFF;
    }
    __syncthreads();
    // sequential write-out (coalesced full lines)
    for (int i = t; i < cnt; i += 256) srcs[base + i] = srt[i];
}

// ---------------------------------------------------------------------------
// gemm1 via MFMA bf16x2 split precision.
// ---------------------------------------------------------------------------
__global__ __launch_bounds__(256) void gemm1_mfma_kernel(const float* __restrict__ x,
                                                         const float* __restrict__ W1,
                                                         const float* __restrict__ dinv,
                                                         unsigned short* __restrict__ hs) {
    __shared__ unsigned short bhi_lds[8192];
    __shared__ unsigned short blo_lds[8192];

    for (int e = threadIdx.x; e < 8192; e += 256) {
        int j    = e & 7;
        int lane = (e >> 3) & 63;
        int pair = e >> 9;
        int kc   = pair >> 2;
        int nt   = pair & 3;
        int k = kc * 32 + (lane >> 4) * 8 + j;
        int n = nt * 16 + (lane & 15);
        float w = W1[k * D_H + n];
        unsigned short hi = f2bf(w);
        float lo = w - bf2f(hi);
        bhi_lds[e] = hi;
        blo_lds[e] = f2bf(lo);
    }
    __syncthreads();

    int wid  = threadIdx.x >> 6;
    int lane = threadIdx.x & 63;
    int quad = lane >> 4;
    int m    = lane & 15;

    int tile = blockIdx.x * 4 + wid;
    if (tile >= M_TILES) return;
    int mbase = tile * 16;

    const float* xr = x + (size_t)(mbase + m) * D_IN + quad * 8;
    short8 ahi[4], alo[4];
    #pragma unroll
    for (int kc = 0; kc < 4; ++kc) {
        floatx4 v0 = *(const floatx4*)(xr + kc * 32);
        floatx4 v1 = *(const floatx4*)(xr + kc * 32 + 4);
        float f[8] = {v0.x, v0.y, v0.z, v0.w, v1.x, v1.y, v1.z, v1.w};
        #pragma unroll
        for (int j = 0; j < 8; ++j) {
            unsigned short hi = f2bf(f[j]);
            float lo = f[j] - bf2f(hi);
            ahi[kc][j] = (short)hi;
            alo[kc][j] = (short)f2bf(lo);
        }
    }

    floatx4 acc[4] = {{0.f,0.f,0.f,0.f},{0.f,0.f,0.f,0.f},{0.f,0.f,0.f,0.f},{0.f,0.f,0.f,0.f}};
    #pragma unroll
    for (int kc = 0; kc < 4; ++kc) {
        #pragma unroll
        for (int nt = 0; nt < 4; ++nt) {
            int fo = ((kc * 4 + nt) * 64 + lane) * 8;
            short8 bhi = *(const short8*)&bhi_lds[fo];
            short8 blo = *(const short8*)&blo_lds[fo];
            acc[nt] = __builtin_amdgcn_mfma_f32_16x16x32_bf16(ahi[kc], bhi, acc[nt], 0, 0, 0);
            acc[nt] = __builtin_amdgcn_mfma_f32_16x16x32_bf16(ahi[kc], blo, acc[nt], 0, 0, 0);
            acc[nt] = __builtin_amdgcn_mfma_f32_16x16x32_bf16(alo[kc], bhi, acc[nt], 0, 0, 0);
        }
    }

    float dv[4];
    #pragma unroll
    for (int r = 0; r < 4; ++r) dv[r] = dinv[mbase + quad * 4 + r];
    #pragma unroll
    for (int nt = 0; nt < 4; ++nt) {
        int col = nt * 16 + m;
        #pragma unroll
        for (int r = 0; r < 4; ++r) {
            int row = mbase + quad * 4 + r;
            hs[row * D_H + col] = f2bf(acc[nt][r] * dv[r]);
        }
    }
}

// Fused layer-1 aggregation + ReLU + layer-2 linear (LDS transpose projection).
__global__ __launch_bounds__(256) void agg1_fused_kernel(const unsigned short* __restrict__ hs,
                                                         const int* __restrict__ offsets,
                                                         const int* __restrict__ srcs,
                                                         const float* __restrict__ dinv,
                                                         const float* __restrict__ b1,
                                                         const float* __restrict__ W2,
                                                         float* __restrict__ h2s) {
    __shared__ float rbuf[256];
    int wid  = threadIdx.x >> 6;
    int lane = threadIdx.x & 63;
    int wave = (blockIdx.x * blockDim.x + threadIdx.x) >> 6;
    int nwaves = (gridDim.x * blockDim.x) >> 6;

    int q = lane >> 4;
    int c = lane & 15;
    float w2c[16];
    #pragma unroll
    for (int j = 0; j < 16; ++j) w2c[j] = W2[(q * 16 + j) * D_OUT + c];
    float bias = b1[lane];
    float* myr = &rbuf[wid * 64];

    for (int node = wave; node < N_NODES; node += nwaves) {
        int beg = offsets[node], end = offsets[node + 1];
        float acc = bf2f(hs[node * D_H + lane]);  // self loop
        int e = beg;
        for (; e + 8 <= end; e += 8) {
            int j0 = srcs[e + 0], j1 = srcs[e + 1], j2 = srcs[e + 2], j3 = srcs[e + 3];
            int j4 = srcs[e + 4], j5 = srcs[e + 5], j6 = srcs[e + 6], j7 = srcs[e + 7];
            float v0 = bf2f(hs[j0 * D_H + lane]);
            float v1 = bf2f(hs[j1 * D_H + lane]);
            float v2 = bf2f(hs[j2 * D_H + lane]);
            float v3 = bf2f(hs[j3 * D_H + lane]);
            float v4 = bf2f(hs[j4 * D_H + lane]);
            float v5 = bf2f(hs[j5 * D_H + lane]);
            float v6 = bf2f(hs[j6 * D_H + lane]);
            float v7 = bf2f(hs[j7 * D_H + lane]);
            acc += ((v0 + v1) + (v2 + v3)) + ((v4 + v5) + (v6 + v7));
        }
        for (; e < end; ++e) {
            acc += bf2f(hs[srcs[e] * D_H + lane]);
        }
        float dv = dinv[node];
        float r = fmaxf(acc * dv + bias, 0.f);

        myr[lane] = r;
        float part = 0.f;
        #pragma unroll
        for (int j = 0; j < 16; ++j) part += myr[q * 16 + j] * w2c[j];
        part += __shfl_xor(part, 16);
        part += __shfl_xor(part, 32);
        if (lane < 16) h2s[node * D_OUT + lane] = part * dv;
    }
}

// out[i][c] = dinv[i]*(h2s[i][c] + sum_{j->i} h2s[j][c]) + b2[c]
__global__ __launch_bounds__(256) void agg2_kernel(const float* __restrict__ h2s,
                                                   const int* __restrict__ offsets,
                                                   const int* __restrict__ srcs,
                                                   const float* __restrict__ dinv,
                                                   const float* __restrict__ b2,
                                                   float* __restrict__ out) {
    int col = threadIdx.x & 15;
    int nidx = (blockIdx.x * blockDim.x + threadIdx.x) >> 4;
    int stride = (gridDim.x * blockDim.x) >> 4;
    for (int node = nidx; node < N_NODES; node += stride) {
        int beg = offsets[node], end = offsets[node + 1];
        float acc = h2s[node * D_OUT + col];  // self loop
        int e = beg;
        for (; e + 8 <= end; e += 8) {
            int j0 = srcs[e + 0], j1 = srcs[e + 1], j2 = srcs[e + 2], j3 = srcs[e + 3];
            int j4 = srcs[e + 4], j5 = srcs[e + 5], j6 = srcs[e + 6], j7 = srcs[e + 7];
            float v0 = h2s[j0 * D_OUT + col];
            float v1 = h2s[j1 * D_OUT + col];
            float v2 = h2s[j2 * D_OUT + col];
            float v3 = h2s[j3 * D_OUT + col];
            float v4 = h2s[j4 * D_OUT + col];
            float v5 = h2s[j5 * D_OUT + col];
            float v6 = h2s[j6 * D_OUT + col];
            float v7 = h2s[j7 * D_OUT + col];
            acc += ((v0 + v1) + (v2 + v3)) + ((v4 + v5) + (v6 + v7));
        }
        for (; e < end; ++e) {
            acc += h2s[srcs[e] * D_OUT + col];
        }
        out[node * D_OUT + col] = acc * dinv[node] + b2[col];
    }
}

extern "C" void kernel_launch(void* const* d_in, const int* in_sizes, int n_in,
                              void* d_out, int out_size, void* d_ws, size_t ws_size,
                              hipStream_t stream) {
    const float* x  = (const float*)d_in[0];
    const int*   ei = (const int*)d_in[1];
    const float* W1 = (const float*)d_in[2];
    const float* b1 = (const float*)d_in[3];
    const float* W2 = (const float*)d_in[4];
    const float* b2 = (const float*)d_in[5];
    float* out = (float*)d_out;

    const int* src = ei;             // edge_index[0]
    const int* dst = ei + N_EDGES;   // edge_index[1]

    char* w = (char*)d_ws;
    int*   cursors  = (int*)(w + 0);
    int*   bases    = (int*)(w + 2048);
    int*   offsets  = (int*)(w + 4096);
    float* dinv     = (float*)(w + 404224);
    int*   srcs     = (int*)(w + 804224);
    unsigned short* hs = (unsigned short*)(w + 7204224);
    float* h2s      = (float*)(w + 20004224);
    int*   region   = (int*)(w + 26404224);

    zero_small_kernel<<<1, 512, 0, stream>>>(cursors);
    bin_kernel<<<G1, 256, 0, stream>>>(src, dst, cursors, region);
    bucket_scan_kernel<<<1, 512, 0, stream>>>(cursors, bases);
    build_kernel<<<NBKT, 256, 0, stream>>>(cursors, bases, region, offsets, dinv, srcs);
    gemm1_mfma_kernel<<<(M_TILES + 3) / 4, 256, 0, stream>>>(x, W1, dinv, hs);
    agg1_fused_kernel<<<6250, 256, 0, stream>>>(hs, offsets, srcs, dinv, b1, W2, h2s);
    agg2_kernel<<<6250, 256, 0, stream>>>(h2s, offsets, srcs, dinv, b2, out);
}

// Round 9
// 225.748 us; speedup vs baseline: 1.7583x; 1.0822x over previous
//
#include <hip/hip_runtime.h>
#include <cstdint>

// Problem constants (from reference)
#define N_NODES 100000
#define N_EDGES 1600000
#define D_IN    128
#define D_H     64
#define D_OUT   16
#define M_TILES 6250  // N_NODES / 16

// Bucket sort parameters
#define NBKT   512
#define NPB    196           // nodes per bucket; 512*196 = 100352 >= N
#define BCAP   4096          // per-bucket region capacity (mean 3125, sd 56 -> +17 sigma)
#define TILE_E 4096          // edges per bin tile (256 thr x 16); N_EDGES % 16 == 0
#define NTILES ((N_EDGES + TILE_E - 1) / TILE_E)   // 391
#define G1     128           // bin_kernel blocks

typedef __attribute__((ext_vector_type(8))) short short8;
typedef __attribute__((ext_vector_type(4))) float floatx4;

// float -> bf16 bits (round to nearest even)
static __device__ __forceinline__ unsigned short f2bf(float f) {
    unsigned int u = __float_as_uint(f);
    u = u + 0x7FFFu + ((u >> 16) & 1u);
    return (unsigned short)(u >> 16);
}
static __device__ __forceinline__ float bf2f(unsigned short h) {
    return __uint_as_float(((unsigned int)h) << 16);
}

// ---------------------------------------------------------------------------
// Workspace layout (bytes, 128-aligned):
//   cursors : NBKT int          @ 0         (2048)
//   offsets : N+1 int           @ 4096      (400004)
//   dinv    : N float           @ 404224    (400000)
//   srcs    : E int (CSR)       @ 804224    (6400000)
//   hs      : N*64 bf16 bits    @ 7204224   (12800000)
//   h2s     : N*16 float        @ 20004224  (6400000)
//   region  : NBKT*BCAP int     @ 26404224  (8388608)
// total ~34.8 MB
// ---------------------------------------------------------------------------

__global__ __launch_bounds__(512) void zero_small_kernel(int* __restrict__ cursors) {
    cursors[threadIdx.x] = 0;
}

// Pass 1: tile-synchronous binning. Per 4096-edge tile: LDS hist over 512
// buckets -> one global atomicAdd per non-empty bucket -> append packed
// (dst_local << 17 | src) entries to the bucket's region (burst appends).
__global__ __launch_bounds__(256) void bin_kernel(const int* __restrict__ src,
                                                  const int* __restrict__ dst,
                                                  int* __restrict__ cursors,
                                                  int* __restrict__ region) {
    __shared__ int hcnt[NBKT];
    __shared__ int hbase[NBKT];
    const int t = threadIdx.x;
    for (int tile = blockIdx.x; tile < NTILES; tile += gridDim.x) {
        for (int i = t; i < NBKT; i += 256) hcnt[i] = 0;
        __syncthreads();
        int e0 = tile * TILE_E + t * 16;
        int pk[16], bk[16], rk[16];
        bool full = (e0 + 16 <= N_EDGES);   // all-or-nothing: N_EDGES % 16 == 0
        if (full) {
            const int4* dp = (const int4*)(dst + e0);
            const int4* sp = (const int4*)(src + e0);
            int dv[16], sv[16];
            #pragma unroll
            for (int q = 0; q < 4; ++q) {
                int4 d4 = dp[q]; int4 s4 = sp[q];
                dv[4*q+0]=d4.x; dv[4*q+1]=d4.y; dv[4*q+2]=d4.z; dv[4*q+3]=d4.w;
                sv[4*q+0]=s4.x; sv[4*q+1]=s4.y; sv[4*q+2]=s4.z; sv[4*q+3]=s4.w;
            }
            #pragma unroll
            for (int k = 0; k < 16; ++k) {
                int d = dv[k];
                int b = d / NPB;          // const divide -> mul/shift
                bk[k] = b;
                pk[k] = ((d - b * NPB) << 17) | sv[k];
                rk[k] = atomicAdd(&hcnt[b], 1);
            }
        }
        __syncthreads();
        for (int i = t; i < NBKT; i += 256) {
            int c = hcnt[i];
            if (c > 0) hbase[i] = atomicAdd(&cursors[i], c);
        }
        __syncthreads();
        if (full) {
            #pragma unroll
            for (int k = 0; k < 16; ++k)
                region[bk[k] * BCAP + hbase[bk[k]] + rk[k]] = pk[k];
        }
        __syncthreads();   // protect hcnt before next tile's clear
    }
}

// Pass 2: one block per bucket. Computes its own base via masked block
// reduction over the 512 bucket counts (folds the old bucket_scan dispatch
// in). Local hist+scan over 196 nodes -> offsets/dinv, sort entries in LDS,
// write CSR segment SEQUENTIALLY (full-line stores).
__global__ __launch_bounds__(256) void build_kernel(const int* __restrict__ cursors,
                                                    const int* __restrict__ region,
                                                    int* __restrict__ offsets,
                                                    float* __restrict__ dinv,
                                                    int* __restrict__ srcs) {
    __shared__ int lhist[NPB];        // counts, then running cursors
    __shared__ int lscan[NPB + 1];
    __shared__ int sbuf[256];
    __shared__ int srt[BCAP];
    __shared__ int red[4];
    int b = blockIdx.x;
    int t = threadIdx.x;

    // base = sum of cursors[i] for i < b  (masked reduction, 512 counts)
    int c0 = cursors[t];
    int c1 = cursors[t + 256];
    int p = ((t < b) ? c0 : 0) + ((t + 256 < b) ? c1 : 0);
    int lane = t & 63, wid = t >> 6;
    #pragma unroll
    for (int off = 32; off > 0; off >>= 1) p += __shfl_down(p, off);
    if (lane == 0) red[wid] = p;
    __syncthreads();
    int base = red[0] + red[1] + red[2] + red[3];
    int cnt = cursors[b];
    const int* reg = region + b * BCAP;

    for (int i = t; i < NPB; i += 256) lhist[i] = 0;
    __syncthreads();
    for (int i = t; i < cnt; i += 256) {
        int ln = reg[i] >> 17;
        atomicAdd(&lhist[ln], 1);
    }
    __syncthreads();
    // exclusive scan of lhist[0..NPB-1]
    int v = (t < NPB) ? lhist[t] : 0;
    sbuf[t] = v;
    __syncthreads();
    for (int off = 1; off < 256; off <<= 1) {
        int u = (t >= off) ? sbuf[t - off] : 0;
        __syncthreads();
        sbuf[t] += u;
        __syncthreads();
    }
    int incl = sbuf[t];
    if (t < NPB) lscan[t] = incl - v;
    if (t == NPB - 1) lscan[NPB] = incl;
    __syncthreads();
    if (t < NPB) lhist[t] = incl - v;   // running cursor = exclusive scan
    __syncthreads();

    // offsets + dinv for this bucket's node range
    int node0 = b * NPB;
    int nlim = N_NODES - node0;
    if (nlim > NPB) nlim = NPB;
    if (t < nlim) {
        offsets[node0 + t] = base + lscan[t];
        int c = lscan[t + 1] - lscan[t];
        dinv[node0 + t] = rsqrtf((float)c + 1.0f);   // +1 self loop
    }
    if (b == (N_NODES - 1) / NPB && t == 0) offsets[N_NODES] = base + cnt;

    // place entries into sorted LDS buffer
    for (int i = t; i < cnt; i += 256) {
        int pk = reg[i];
        int ln = pk >> 17;
        int pos = atomicAdd(&lhist[ln], 1);
        srt[pos] = pk & 0x1FFFF;
    }
    __syncthreads();
    // sequential write-out (coalesced full lines)
    for (int i = t; i < cnt; i += 256) srcs[base + i] = srt[i];
}

// ---------------------------------------------------------------------------
// gemm1 via MFMA bf16x2 split precision.
// ---------------------------------------------------------------------------
__global__ __launch_bounds__(256) void gemm1_mfma_kernel(const float* __restrict__ x,
                                                         const float* __restrict__ W1,
                                                         const float* __restrict__ dinv,
                                                         unsigned short* __restrict__ hs) {
    __shared__ unsigned short bhi_lds[8192];
    __shared__ unsigned short blo_lds[8192];

    for (int e = threadIdx.x; e < 8192; e += 256) {
        int j    = e & 7;
        int lane = (e >> 3) & 63;
        int pair = e >> 9;
        int kc   = pair >> 2;
        int nt   = pair & 3;
        int k = kc * 32 + (lane >> 4) * 8 + j;
        int n = nt * 16 + (lane & 15);
        float w = W1[k * D_H + n];
        unsigned short hi = f2bf(w);
        float lo = w - bf2f(hi);
        bhi_lds[e] = hi;
        blo_lds[e] = f2bf(lo);
    }
    __syncthreads();

    int wid  = threadIdx.x >> 6;
    int lane = threadIdx.x & 63;
    int quad = lane >> 4;
    int m    = lane & 15;

    int tile = blockIdx.x * 4 + wid;
    if (tile >= M_TILES) return;
    int mbase = tile * 16;

    const float* xr = x + (size_t)(mbase + m) * D_IN + quad * 8;
    short8 ahi[4], alo[4];
    #pragma unroll
    for (int kc = 0; kc < 4; ++kc) {
        floatx4 v0 = *(const floatx4*)(xr + kc * 32);
        floatx4 v1 = *(const floatx4*)(xr + kc * 32 + 4);
        float f[8] = {v0.x, v0.y, v0.z, v0.w, v1.x, v1.y, v1.z, v1.w};
        #pragma unroll
        for (int j = 0; j < 8; ++j) {
            unsigned short hi = f2bf(f[j]);
            float lo = f[j] - bf2f(hi);
            ahi[kc][j] = (short)hi;
            alo[kc][j] = (short)f2bf(lo);
        }
    }

    floatx4 acc[4] = {{0.f,0.f,0.f,0.f},{0.f,0.f,0.f,0.f},{0.f,0.f,0.f,0.f},{0.f,0.f,0.f,0.f}};
    #pragma unroll
    for (int kc = 0; kc < 4; ++kc) {
        #pragma unroll
        for (int nt = 0; nt < 4; ++nt) {
            int fo = ((kc * 4 + nt) * 64 + lane) * 8;
            short8 bhi = *(const short8*)&bhi_lds[fo];
            short8 blo = *(const short8*)&blo_lds[fo];
            acc[nt] = __builtin_amdgcn_mfma_f32_16x16x32_bf16(ahi[kc], bhi, acc[nt], 0, 0, 0);
            acc[nt] = __builtin_amdgcn_mfma_f32_16x16x32_bf16(ahi[kc], blo, acc[nt], 0, 0, 0);
            acc[nt] = __builtin_amdgcn_mfma_f32_16x16x32_bf16(alo[kc], bhi, acc[nt], 0, 0, 0);
        }
    }

    float dv[4];
    #pragma unroll
    for (int r = 0; r < 4; ++r) dv[r] = dinv[mbase + quad * 4 + r];
    #pragma unroll
    for (int nt = 0; nt < 4; ++nt) {
        int col = nt * 16 + m;
        #pragma unroll
        for (int r = 0; r < 4; ++r) {
            int row = mbase + quad * 4 + r;
            hs[row * D_H + col] = f2bf(acc[nt][r] * dv[r]);
        }
    }
}

// Fused layer-1 aggregation + ReLU + layer-2 linear (LDS transpose projection).
// Edge gathers in clamped batches of 16: indices clamped to stay in-bounds,
// adds masked by (k < rem) -> 16 outstanding gathers, no serial tail loop.
__global__ __launch_bounds__(256) void agg1_fused_kernel(const unsigned short* __restrict__ hs,
                                                         const int* __restrict__ offsets,
                                                         const int* __restrict__ srcs,
                                                         const float* __restrict__ dinv,
                                                         const float* __restrict__ b1,
                                                         const float* __restrict__ W2,
                                                         float* __restrict__ h2s) {
    __shared__ float rbuf[256];
    int wid  = threadIdx.x >> 6;
    int lane = threadIdx.x & 63;
    int wave = (blockIdx.x * blockDim.x + threadIdx.x) >> 6;
    int nwaves = (gridDim.x * blockDim.x) >> 6;

    int q = lane >> 4;
    int c = lane & 15;
    float w2c[16];
    #pragma unroll
    for (int j = 0; j < 16; ++j) w2c[j] = W2[(q * 16 + j) * D_OUT + c];
    float bias = b1[lane];
    float* myr = &rbuf[wid * 64];

    for (int node = wave; node < N_NODES; node += nwaves) {
        int beg = offsets[node], end = offsets[node + 1];
        float acc = bf2f(hs[node * D_H + lane]);  // self loop
        for (int e = beg; e < end; e += 16) {
            int rem = end - e;
            int jj[16];
            #pragma unroll
            for (int k = 0; k < 16; ++k) {
                int idx = e + k;
                if (idx > N_EDGES - 1) idx = N_EDGES - 1;  // stay in srcs[]
                jj[k] = srcs[idx];                          // wave-uniform scalar loads
            }
            float vv[16];
            #pragma unroll
            for (int k = 0; k < 16; ++k) vv[k] = bf2f(hs[jj[k] * D_H + lane]);
            #pragma unroll
            for (int k = 0; k < 16; ++k) acc += (k < rem) ? vv[k] : 0.f;
        }
        float dv = dinv[node];
        float r = fmaxf(acc * dv + bias, 0.f);

        myr[lane] = r;
        float part = 0.f;
        #pragma unroll
        for (int j = 0; j < 16; ++j) part += myr[q * 16 + j] * w2c[j];
        part += __shfl_xor(part, 16);
        part += __shfl_xor(part, 32);
        if (lane < 16) h2s[node * D_OUT + lane] = part * dv;
    }
}

// out[i][c] = dinv[i]*(h2s[i][c] + sum_{j->i} h2s[j][c]) + b2[c]
// 16 threads per node; clamped 16-wide gather batches.
__global__ __launch_bounds__(256) void agg2_kernel(const float* __restrict__ h2s,
                                                   const int* __restrict__ offsets,
                                                   const int* __restrict__ srcs,
                                                   const float* __restrict__ dinv,
                                                   const float* __restrict__ b2,
                                                   float* __restrict__ out) {
    int col = threadIdx.x & 15;
    int nidx = (blockIdx.x * blockDim.x + threadIdx.x) >> 4;
    int stride = (gridDim.x * blockDim.x) >> 4;
    for (int node = nidx; node < N_NODES; node += stride) {
        int beg = offsets[node], end = offsets[node + 1];
        float acc = h2s[node * D_OUT + col];  // self loop
        for (int e = beg; e < end; e += 16) {
            int rem = end - e;
            int jj[16];
            #pragma unroll
            for (int k = 0; k < 16; ++k) {
                int idx = e + k;
                if (idx > N_EDGES - 1) idx = N_EDGES - 1;
                jj[k] = srcs[idx];
            }
            float vv[16];
            #pragma unroll
            for (int k = 0; k < 16; ++k) vv[k] = h2s[jj[k] * D_OUT + col];
            #pragma unroll
            for (int k = 0; k < 16; ++k) acc += (k < rem) ? vv[k] : 0.f;
        }
        out[node * D_OUT + col] = acc * dinv[node] + b2[col];
    }
}

extern "C" void kernel_launch(void* const* d_in, const int* in_sizes, int n_in,
                              void* d_out, int out_size, void* d_ws, size_t ws_size,
                              hipStream_t stream) {
    const float* x  = (const float*)d_in[0];
    const int*   ei = (const int*)d_in[1];
    const float* W1 = (const float*)d_in[2];
    const float* b1 = (const float*)d_in[3];
    const float* W2 = (const float*)d_in[4];
    const float* b2 = (const float*)d_in[5];
    float* out = (float*)d_out;

    const int* src = ei;             // edge_index[0]
    const int* dst = ei + N_EDGES;   // edge_index[1]

    char* w = (char*)d_ws;
    int*   cursors  = (int*)(w + 0);
    int*   offsets  = (int*)(w + 4096);
    float* dinv     = (float*)(w + 404224);
    int*   srcs     = (int*)(w + 804224);
    unsigned short* hs = (unsigned short*)(w + 7204224);
    float* h2s      = (float*)(w + 20004224);
    int*   region   = (int*)(w + 26404224);

    zero_small_kernel<<<1, 512, 0, stream>>>(cursors);
    bin_kernel<<<G1, 256, 0, stream>>>(src, dst, cursors, region);
    build_kernel<<<NBKT, 256, 0, stream>>>(cursors, region, offsets, dinv, srcs);
    gemm1_mfma_kernel<<<(M_TILES + 3) / 4, 256, 0, stream>>>(x, W1, dinv, hs);
    agg1_fused_kernel<<<6250, 256, 0, stream>>>(hs, offsets, srcs, dinv, b1, W2, h2s);
    agg2_kernel<<<6250, 256, 0, stream>>>(h2s, offsets, srcs, dinv, b2, out);
}

// Round 11
// 206.435 us; speedup vs baseline: 1.9228x; 1.0936x over previous
//
#include <hip/hip_runtime.h>
#include <cstdint>

// Problem constants (from reference)
#define N_NODES 100000
#define N_EDGES 1600000
#define D_IN    128
#define D_H     64
#define D_OUT   16
#define M_TILES 6250  // N_NODES / 16

// Bucket sort parameters
#define NBKT   512
#define NPB    196           // nodes per bucket; 512*196 = 100352 >= N
#define BCAP   4096          // per-bucket region capacity (mean 3125, sd 56 -> +17 sigma)
#define TILE_E 4096          // edges per bin tile (256 thr x 16); N_EDGES % 16 == 0
#define NTILES ((N_EDGES + TILE_E - 1) / TILE_E)   // 391
#define G1     128           // bin_kernel blocks

typedef __attribute__((ext_vector_type(8))) short short8;
typedef __attribute__((ext_vector_type(4))) float floatx4;

// float -> bf16 bits (round to nearest even)
static __device__ __forceinline__ unsigned short f2bf(float f) {
    unsigned int u = __float_as_uint(f);
    u = u + 0x7FFFu + ((u >> 16) & 1u);
    return (unsigned short)(u >> 16);
}
static __device__ __forceinline__ float bf2f(unsigned short h) {
    return __uint_as_float(((unsigned int)h) << 16);
}

// ---------------------------------------------------------------------------
// Workspace layout (bytes, 128-aligned). R10 BUG FIX: srcs is E+16 ints
// (6400064 B) for the gather-batch pad; hs/h2s/region shifted up so the pad
// no longer overlaps hs (the R10 crash: gemm1 overwrote the pad with bf16
// bits, agg1 used them as indices -> wild gather -> fault).
//   cursors : NBKT int          @ 0
//   offsets : N+1 int           @ 4096
//   dinv    : N float           @ 404224
//   srcs    : E+16 int (CSR)    @ 804224    (ends 7204288)
//   hs      : N*64 bf16 bits    @ 7204352   (ends 20004352)
//   h2s     : N*16 float        @ 20004480  (ends 26404480)
//   region  : NBKT*BCAP int     @ 26404480  (ends 34793088)
// total ~34.8 MB
// ---------------------------------------------------------------------------

__global__ __launch_bounds__(512) void zero_small_kernel(int* __restrict__ cursors,
                                                         int* __restrict__ srcs) {
    cursors[threadIdx.x] = 0;
    if (threadIdx.x < 16) srcs[N_EDGES + threadIdx.x] = 0;  // gather-batch pad
}

// Pass 1: tile-synchronous binning. Per 4096-edge tile: LDS hist over 512
// buckets -> one global atomicAdd per non-empty bucket -> append packed
// (dst_local << 17 | src) entries to the bucket's region (burst appends).
__global__ __launch_bounds__(256) void bin_kernel(const int* __restrict__ src,
                                                  const int* __restrict__ dst,
                                                  int* __restrict__ cursors,
                                                  int* __restrict__ region) {
    __shared__ int hcnt[NBKT];
    __shared__ int hbase[NBKT];
    const int t = threadIdx.x;
    for (int tile = blockIdx.x; tile < NTILES; tile += gridDim.x) {
        for (int i = t; i < NBKT; i += 256) hcnt[i] = 0;
        __syncthreads();
        int e0 = tile * TILE_E + t * 16;
        int pk[16], bk[16], rk[16];
        bool full = (e0 + 16 <= N_EDGES);   // all-or-nothing: N_EDGES % 16 == 0
        if (full) {
            const int4* dp = (const int4*)(dst + e0);
            const int4* sp = (const int4*)(src + e0);
            int dv[16], sv[16];
            #pragma unroll
            for (int q = 0; q < 4; ++q) {
                int4 d4 = dp[q]; int4 s4 = sp[q];
                dv[4*q+0]=d4.x; dv[4*q+1]=d4.y; dv[4*q+2]=d4.z; dv[4*q+3]=d4.w;
                sv[4*q+0]=s4.x; sv[4*q+1]=s4.y; sv[4*q+2]=s4.z; sv[4*q+3]=s4.w;
            }
            #pragma unroll
            for (int k = 0; k < 16; ++k) {
                int d = dv[k];
                int b = d / NPB;          // const divide -> mul/shift
                bk[k] = b;
                pk[k] = ((d - b * NPB) << 17) | sv[k];
                rk[k] = atomicAdd(&hcnt[b], 1);
            }
        }
        __syncthreads();
        for (int i = t; i < NBKT; i += 256) {
            int c = hcnt[i];
            if (c > 0) hbase[i] = atomicAdd(&cursors[i], c);
        }
        __syncthreads();
        if (full) {
            #pragma unroll
            for (int k = 0; k < 16; ++k)
                region[bk[k] * BCAP + hbase[bk[k]] + rk[k]] = pk[k];
        }
        __syncthreads();   // protect hcnt before next tile's clear
    }
}

// Pass 2: one block per bucket. Computes its own base via masked block
// reduction over the 512 bucket counts. Local hist+scan over 196 nodes ->
// offsets/dinv, sort entries in LDS, write CSR segment SEQUENTIALLY.
__global__ __launch_bounds__(256) void build_kernel(const int* __restrict__ cursors,
                                                    const int* __restrict__ region,
                                                    int* __restrict__ offsets,
                                                    float* __restrict__ dinv,
                                                    int* __restrict__ srcs) {
    __shared__ int lhist[NPB];        // counts, then running cursors
    __shared__ int lscan[NPB + 1];
    __shared__ int sbuf[256];
    __shared__ int srt[BCAP];
    __shared__ int red[4];
    int b = blockIdx.x;
    int t = threadIdx.x;

    // base = sum of cursors[i] for i < b  (masked reduction, 512 counts)
    int c0 = cursors[t];
    int c1 = cursors[t + 256];
    int p = ((t < b) ? c0 : 0) + ((t + 256 < b) ? c1 : 0);
    int lane = t & 63, wid = t >> 6;
    #pragma unroll
    for (int off = 32; off > 0; off >>= 1) p += __shfl_down(p, off);
    if (lane == 0) red[wid] = p;
    __syncthreads();
    int base = red[0] + red[1] + red[2] + red[3];
    int cnt = cursors[b];
    const int* reg = region + b * BCAP;

    for (int i = t; i < NPB; i += 256) lhist[i] = 0;
    __syncthreads();
    for (int i = t; i < cnt; i += 256) {
        int ln = reg[i] >> 17;
        atomicAdd(&lhist[ln], 1);
    }
    __syncthreads();
    // exclusive scan of lhist[0..NPB-1]
    int v = (t < NPB) ? lhist[t] : 0;
    sbuf[t] = v;
    __syncthreads();
    for (int off = 1; off < 256; off <<= 1) {
        int u = (t >= off) ? sbuf[t - off] : 0;
        __syncthreads();
        sbuf[t] += u;
        __syncthreads();
    }
    int incl = sbuf[t];
    if (t < NPB) lscan[t] = incl - v;
    if (t == NPB - 1) lscan[NPB] = incl;
    __syncthreads();
    if (t < NPB) lhist[t] = incl - v;   // running cursor = exclusive scan
    __syncthreads();

    // offsets + dinv for this bucket's node range
    int node0 = b * NPB;
    int nlim = N_NODES - node0;
    if (nlim > NPB) nlim = NPB;
    if (t < nlim) {
        offsets[node0 + t] = base + lscan[t];
        int c = lscan[t + 1] - lscan[t];
        dinv[node0 + t] = rsqrtf((float)c + 1.0f);   // +1 self loop
    }
    if (b == (N_NODES - 1) / NPB && t == 0) offsets[N_NODES] = base + cnt;

    // place entries into sorted LDS buffer
    for (int i = t; i < cnt; i += 256) {
        int pk = reg[i];
        int ln = pk >> 17;
        int pos = atomicAdd(&lhist[ln], 1);
        srt[pos] = pk & 0x1FFFF;
    }
    __syncthreads();
    // sequential write-out (coalesced full lines)
    for (int i = t; i < cnt; i += 256) srcs[base + i] = srt[i];
}

// ---------------------------------------------------------------------------
// gemm1 via MFMA bf16x2 split precision.
// ---------------------------------------------------------------------------
__global__ __launch_bounds__(256) void gemm1_mfma_kernel(const float* __restrict__ x,
                                                         const float* __restrict__ W1,
                                                         const float* __restrict__ dinv,
                                                         unsigned short* __restrict__ hs) {
    __shared__ unsigned short bhi_lds[8192];
    __shared__ unsigned short blo_lds[8192];

    for (int e = threadIdx.x; e < 8192; e += 256) {
        int j    = e & 7;
        int lane = (e >> 3) & 63;
        int pair = e >> 9;
        int kc   = pair >> 2;
        int nt   = pair & 3;
        int k = kc * 32 + (lane >> 4) * 8 + j;
        int n = nt * 16 + (lane & 15);
        float w = W1[k * D_H + n];
        unsigned short hi = f2bf(w);
        float lo = w - bf2f(hi);
        bhi_lds[e] = hi;
        blo_lds[e] = f2bf(lo);
    }
    __syncthreads();

    int wid  = threadIdx.x >> 6;
    int lane = threadIdx.x & 63;
    int quad = lane >> 4;
    int m    = lane & 15;

    int tile = blockIdx.x * 4 + wid;
    if (tile >= M_TILES) return;
    int mbase = tile * 16;

    const float* xr = x + (size_t)(mbase + m) * D_IN + quad * 8;
    short8 ahi[4], alo[4];
    #pragma unroll
    for (int kc = 0; kc < 4; ++kc) {
        floatx4 v0 = *(const floatx4*)(xr + kc * 32);
        floatx4 v1 = *(const floatx4*)(xr + kc * 32 + 4);
        float f[8] = {v0.x, v0.y, v0.z, v0.w, v1.x, v1.y, v1.z, v1.w};
        #pragma unroll
        for (int j = 0; j < 8; ++j) {
            unsigned short hi = f2bf(f[j]);
            float lo = f[j] - bf2f(hi);
            ahi[kc][j] = (short)hi;
            alo[kc][j] = (short)f2bf(lo);
        }
    }

    floatx4 acc[4] = {{0.f,0.f,0.f,0.f},{0.f,0.f,0.f,0.f},{0.f,0.f,0.f,0.f},{0.f,0.f,0.f,0.f}};
    #pragma unroll
    for (int kc = 0; kc < 4; ++kc) {
        #pragma unroll
        for (int nt = 0; nt < 4; ++nt) {
            int fo = ((kc * 4 + nt) * 64 + lane) * 8;
            short8 bhi = *(const short8*)&bhi_lds[fo];
            short8 blo = *(const short8*)&blo_lds[fo];
            acc[nt] = __builtin_amdgcn_mfma_f32_16x16x32_bf16(ahi[kc], bhi, acc[nt], 0, 0, 0);
            acc[nt] = __builtin_amdgcn_mfma_f32_16x16x32_bf16(ahi[kc], blo, acc[nt], 0, 0, 0);
            acc[nt] = __builtin_amdgcn_mfma_f32_16x16x32_bf16(alo[kc], bhi, acc[nt], 0, 0, 0);
        }
    }

    float dv[4];
    #pragma unroll
    for (int r = 0; r < 4; ++r) dv[r] = dinv[mbase + quad * 4 + r];
    #pragma unroll
    for (int nt = 0; nt < 4; ++nt) {
        int col = nt * 16 + m;
        #pragma unroll
        for (int r = 0; r < 4; ++r) {
            int row = mbase + quad * 4 + r;
            hs[row * D_H + col] = f2bf(acc[nt][r] * dv[r]);
        }
    }
}

// Fused layer-1 aggregation + ReLU + layer-2 linear (LDS transpose projection).
// Gather indices are wave-uniform -> forced onto the scalar path via
// readfirstlane: hs gathers use SGPR base + loop-invariant lane offset (zero
// per-edge vector address math). Tail masking via uniform-float fmac (1 VALU).
// srcs is padded with 16 zeros (pad loads are in-bounds; adds masked to 0).
__global__ __launch_bounds__(256) void agg1_fused_kernel(const unsigned short* __restrict__ hs,
                                                         const int* __restrict__ offsets,
                                                         const int* __restrict__ srcs,
                                                         const float* __restrict__ dinv,
                                                         const float* __restrict__ b1,
                                                         const float* __restrict__ W2,
                                                         float* __restrict__ h2s) {
    __shared__ float rbuf[256];
    int wid  = threadIdx.x >> 6;
    int lane = threadIdx.x & 63;
    int wave = (blockIdx.x * blockDim.x + threadIdx.x) >> 6;
    int nwaves = (gridDim.x * blockDim.x) >> 6;

    int q = lane >> 4;
    int c = lane & 15;
    float w2c[16];
    #pragma unroll
    for (int j = 0; j < 16; ++j) w2c[j] = W2[(q * 16 + j) * D_OUT + c];
    float bias = b1[lane];
    float* myr = &rbuf[wid * 64];

    for (int node = wave; node < N_NODES; node += nwaves) {
        int beg = __builtin_amdgcn_readfirstlane(offsets[node]);
        int end = __builtin_amdgcn_readfirstlane(offsets[node + 1]);
        float acc = bf2f(hs[node * D_H + lane]);  // self loop
        for (int e = beg; e < end; e += 16) {
            int rem = end - e;
            const int* ep = srcs + e;
            int jj[16];
            #pragma unroll
            for (int k = 0; k < 16; ++k)
                jj[k] = __builtin_amdgcn_readfirstlane(ep[k]);  // uniform -> SGPR
            float vv[16];
            #pragma unroll
            for (int k = 0; k < 16; ++k) {
                const unsigned short* hp = hs + (size_t)jj[k] * D_H;  // SGPR base
                vv[k] = bf2f(hp[lane]);
            }
            #pragma unroll
            for (int k = 0; k < 16; ++k) {
                float m = (k < rem) ? 1.0f : 0.0f;   // uniform (SGPR) mask
                acc = fmaf(vv[k], m, acc);
            }
        }
        float dv = dinv[node];
        float r = fmaxf(acc * dv + bias, 0.f);

        myr[lane] = r;
        float part = 0.f;
        #pragma unroll
        for (int j = 0; j < 16; ++j) part += myr[q * 16 + j] * w2c[j];
        part += __shfl_xor(part, 16);
        part += __shfl_xor(part, 32);
        if (lane < 16) h2s[node * D_OUT + lane] = part * dv;
    }
}

// out[i][c] = dinv[i]*(h2s[i][c] + sum_{j->i} h2s[j][c]) + b2[c]
// 16 threads per node; padded srcs (no clamp), fmac-masked 16-wide batches.
__global__ __launch_bounds__(256) void agg2_kernel(const float* __restrict__ h2s,
                                                   const int* __restrict__ offsets,
                                                   const int* __restrict__ srcs,
                                                   const float* __restrict__ dinv,
                                                   const float* __restrict__ b2,
                                                   float* __restrict__ out) {
    int col = threadIdx.x & 15;
    int nidx = (blockIdx.x * blockDim.x + threadIdx.x) >> 4;
    int stride = (gridDim.x * blockDim.x) >> 4;
    for (int node = nidx; node < N_NODES; node += stride) {
        int beg = offsets[node], end = offsets[node + 1];
        float acc = h2s[node * D_OUT + col];  // self loop
        for (int e = beg; e < end; e += 16) {
            int rem = end - e;
            const int* ep = srcs + e;
            int jj[16];
            #pragma unroll
            for (int k = 0; k < 16; ++k) jj[k] = ep[k];
            float vv[16];
            #pragma unroll
            for (int k = 0; k < 16; ++k) vv[k] = h2s[jj[k] * D_OUT + col];
            #pragma unroll
            for (int k = 0; k < 16; ++k) {
                float m = (k < rem) ? 1.0f : 0.0f;
                acc = fmaf(vv[k], m, acc);
            }
        }
        out[node * D_OUT + col] = acc * dinv[node] + b2[col];
    }
}

extern "C" void kernel_launch(void* const* d_in, const int* in_sizes, int n_in,
                              void* d_out, int out_size, void* d_ws, size_t ws_size,
                              hipStream_t stream) {
    const float* x  = (const float*)d_in[0];
    const int*   ei = (const int*)d_in[1];
    const float* W1 = (const float*)d_in[2];
    const float* b1 = (const float*)d_in[3];
    const float* W2 = (const float*)d_in[4];
    const float* b2 = (const float*)d_in[5];
    float* out = (float*)d_out;

    const int* src = ei;             // edge_index[0]
    const int* dst = ei + N_EDGES;   // edge_index[1]

    char* w = (char*)d_ws;
    int*   cursors  = (int*)(w + 0);
    int*   offsets  = (int*)(w + 4096);
    float* dinv     = (float*)(w + 404224);
    int*   srcs     = (int*)(w + 804224);
    unsigned short* hs = (unsigned short*)(w + 7204352);   // shifted: pad no longer overlaps
    float* h2s      = (float*)(w + 20004480);
    int*   region   = (int*)(w + 26404480);

    zero_small_kernel<<<1, 512, 0, stream>>>(cursors, srcs);
    bin_kernel<<<G1, 256, 0, stream>>>(src, dst, cursors, region);
    build_kernel<<<NBKT, 256, 0, stream>>>(cursors, region, offsets, dinv, srcs);
    gemm1_mfma_kernel<<<(M_TILES + 3) / 4, 256, 0, stream>>>(x, W1, dinv, hs);
    agg1_fused_kernel<<<6250, 256, 0, stream>>>(hs, offsets, srcs, dinv, b1, W2, h2s);
    agg2_kernel<<<6250, 256, 0, stream>>>(h2s, offsets, srcs, dinv, b2, out);
}